// Round 4
// baseline (424.015 us; speedup 1.0000x reference)
//
#include <hip/hip_runtime.h>
#include <math.h>
#include <float.h>

#define IN_DIM   1024
#define OUT_DIM  128
#define MEM_LEN  131072
#define GRID     8192
#define DIST_BLOCKS 2048   // blocks that also run the distance pass

#define NA_FLOATS  ((long long)MEM_LEN * OUT_DIM)   // 16,777,216
#define NB_FLOATS  ((long long)MEM_LEN * IN_DIM)    // 134,217,728
#define N_TOTAL    (NA_FLOATS + NB_FLOATS)          // 150,994,944
#define NA_CHUNKS  (NA_FLOATS / 4)                  // 4,194,304
#define CMAX       ((N_TOTAL - 4) / 4)              // 37,748,735 last full dst chunk
#define NGROUPS    ((CMAX + 255) / 256)             // 147,456 (last group partial)
#define STRADDLE_G 16383                            // group whose sources straddle regions

// insert (v,i) into ascending-(v,i) top-3; lexicographic tie-break matches
// jax.lax.top_k stability (lower index wins on equal distance)
__device__ __forceinline__ void ins3(float v, int i,
    float& v0, int& i0, float& v1, int& i1, float& v2, int& i2) {
  if (v < v0 || (v == v0 && i < i0)) {
    v2 = v1; i2 = i1; v1 = v0; i1 = i0; v0 = v; i0 = i;
  } else if (v < v1 || (v == v1 && i < i1)) {
    v2 = v1; i2 = i1; v1 = v; i1 = i;
  } else if (v < v2 || (v == v2 && i < i2)) {
    v2 = v; i2 = i;
  }
}

// K1: normalize + encoder + decoder-MSE + win_loss. Single block, 1024 threads.
__global__ __launch_bounds__(1024) void k1_encode(
    const float* __restrict__ x, const float* __restrict__ mean,
    const float* __restrict__ stdv, const float* __restrict__ W_enc,
    const float* __restrict__ b_enc, const float* __restrict__ W_dec,
    const float* __restrict__ b_dec, const float* __restrict__ win_mean,
    const float* __restrict__ win_std,
    float* __restrict__ ws_enc, float* __restrict__ ws_winloss) {
  __shared__ float s_new[IN_DIM];
  __shared__ float s_part[8][OUT_DIM];
  __shared__ float s_enc[OUT_DIM];
  __shared__ float s_red[16];
  const int t = threadIdx.x;
  const float sd = stdv[t];
  const float nv = (sd == 0.0f) ? 0.0f : (x[t] - mean[t]) / sd;
  s_new[t] = nv;
  __syncthreads();
  const int o = t & (OUT_DIM - 1);
  const int p = t >> 7;
  float partial = 0.0f;
  #pragma unroll 8
  for (int i = 0; i < 128; ++i) {
    const int k = p * 128 + i;
    partial += s_new[k] * W_enc[k * OUT_DIM + o];
  }
  s_part[p][o] = partial;
  __syncthreads();
  if (t < OUT_DIM) {
    float sum = b_enc[t];
    #pragma unroll
    for (int pp = 0; pp < 8; ++pp) sum += s_part[pp][t];
    const float e = tanhf(sum);
    s_enc[t] = e;
    ws_enc[t] = e;
  }
  __syncthreads();
  float r = b_dec[t];
  #pragma unroll 8
  for (int k = 0; k < OUT_DIM; ++k) r += s_enc[k] * W_dec[k * IN_DIM + t];
  const float diff = r - nv;
  float sq = diff * diff;
  for (int off = 32; off; off >>= 1) sq += __shfl_xor(sq, off, 64);
  const int lane = t & 63, wid = t >> 6;
  if (lane == 0) s_red[wid] = sq;
  __syncthreads();
  if (t == 0) {
    float tot = 0.0f;
    #pragma unroll
    for (int w = 0; w < 16; ++w) tot += s_red[w];
    const float mse = tot / (float)IN_DIM;
    const float z = (mse - win_mean[0]) / win_std[0];
    const float prob = 0.5f * erfcf(-z * 0.70710678118654752440f); // ndtr
    ws_winloss[0] = (1.0f - prob) * mse;  // SKIP_THRESHOLD == 1
  }
}

// Fused: (blocks < DIST_BLOCKS) L1-distance scan, then ALL blocks do the
// realigned copy out[1..N_TOTAL] <- {memory, mem_data}, 64B per lane:
// lane owns store chunks b+1..b+4 (b = g*256 + 4*lane); loads V[b+1..b+4];
// V[b].w arrives from lane-1 via ONE shfl per 64B (lane 0: scalar load).
__global__ __launch_bounds__(256) void k2_fused(
    const float* __restrict__ memory, const float* __restrict__ mem_data,
    const float* __restrict__ ws_enc, float* __restrict__ out,
    float* __restrict__ topv, int* __restrict__ topi) {
  const int t = threadIdx.x;
  const int lane = t & 63;
  const int wid  = t >> 6;
  const float4* mem4 = reinterpret_cast<const float4*>(memory);
  const float4* md4  = reinterpret_cast<const float4*>(mem_data);

  // ---- phase 1: distances (16 rows/wave, blocks < DIST_BLOCKS only) ----
  if (blockIdx.x < DIST_BLOCKS) {
    const float2 e = reinterpret_cast<const float2*>(ws_enc)[lane];
    float v0 = FLT_MAX, v1 = FLT_MAX, v2 = FLT_MAX;
    int i0 = 0x7fffffff, i1 = 0x7fffffff, i2 = 0x7fffffff;
    const int r0 = (blockIdx.x * 4 + wid) * 16;
    for (int rr = 0; rr < 16; ++rr) {
      const int r = r0 + rr;
      const float2 m = reinterpret_cast<const float2*>(memory)[(size_t)r * 64 + lane];
      float d = fabsf(m.x - e.x) + fabsf(m.y - e.y);
      for (int off = 32; off; off >>= 1) d += __shfl_xor(d, off, 64);
      ins3(d, r, v0, i0, v1, i1, v2, i2);
    }
    __shared__ float sv[4][3];
    __shared__ int   si[4][3];
    if (lane == 0) {
      sv[wid][0] = v0; sv[wid][1] = v1; sv[wid][2] = v2;
      si[wid][0] = i0; si[wid][1] = i1; si[wid][2] = i2;
    }
    __syncthreads();
    if (t == 0) {
      for (int w = 1; w < 4; ++w)
        for (int j = 0; j < 3; ++j)
          ins3(sv[w][j], si[w][j], v0, i0, v1, i1, v2, i2);
      topv[blockIdx.x * 3 + 0] = v0; topi[blockIdx.x * 3 + 0] = i0;
      topv[blockIdx.x * 3 + 1] = v1; topi[blockIdx.x * 3 + 1] = i1;
      topv[blockIdx.x * 3 + 2] = v2; topi[blockIdx.x * 3 + 2] = i2;
    }
  }

  // ---- phase 2: realigned copy ----
  for (long long g = (long long)blockIdx.x * 4 + wid; g < NGROUPS;
       g += (long long)GRID * 4) {
    const long long b = g * 256 + (long long)lane * 4;  // stores b+1..b+4
    if (g != STRADDLE_G && g < NGROUPS - 1) {
      // fast path: single source region, all chunks valid
      const float4* src = (g < STRADDLE_G) ? mem4 : (md4 - NA_CHUNKS);
      const float4 a0 = src[b + 1];
      const float4 a1 = src[b + 2];
      const float4 a2 = src[b + 3];
      const float4 a3 = src[b + 4];
      float prev = __shfl_up(a3.w, 1, 64);
      if (lane == 0) {
        const long long s = 1024LL * g + 3;   // dword V[b].w for lane 0
        prev = (s < NA_FLOATS) ? memory[s] : mem_data[s - NA_FLOATS];
      }
      float4* o4 = reinterpret_cast<float4*>(out + 4 * b + 4);
      o4[0] = make_float4(prev, a0.x, a0.y, a0.z);
      o4[1] = make_float4(a0.w, a1.x, a1.y, a1.z);
      o4[2] = make_float4(a1.w, a2.x, a2.y, a2.z);
      o4[3] = make_float4(a2.w, a3.x, a3.y, a3.z);
    } else {
      // slow path: region straddle and/or partial last group
      float4 av[4];
      #pragma unroll
      for (int m = 0; m < 4; ++m) {
        const long long c = b + 1 + m;
        av[m] = (c <= CMAX)
                  ? ((c < NA_CHUNKS) ? mem4[c] : md4[c - NA_CHUNKS])
                  : make_float4(0.f, 0.f, 0.f, 0.f);
      }
      float prev = __shfl_up(av[3].w, 1, 64);
      if (lane == 0) {
        const long long s = 1024LL * g + 3;
        prev = (s < NA_FLOATS) ? memory[s] : mem_data[s - NA_FLOATS];
      }
      float wprev = prev;
      #pragma unroll
      for (int m = 0; m < 4; ++m) {
        const long long c = b + 1 + m;
        if (c <= CMAX)
          *reinterpret_cast<float4*>(out + 4 * c) =
              make_float4(wprev, av[m].x, av[m].y, av[m].z);
        wprev = av[m].w;
      }
    }
  }
  if (blockIdx.x == 0 && t == 0) {
    out[1] = memory[0]; out[2] = memory[1]; out[3] = memory[2];
    out[N_TOTAL] = mem_data[NB_FLOATS - 1];
  }
}

// K3+K4: merge candidates, final loss, conditional FIFO row update.
__global__ __launch_bounds__(1024) void k3_topk_update(
    const float* __restrict__ topv, const int* __restrict__ topi,
    const float* __restrict__ ws_winloss, const float* __restrict__ ws_enc,
    const float* __restrict__ x, float* __restrict__ out_loss,
    float* __restrict__ out_mem, float* __restrict__ out_md) {
  const int t = threadIdx.x;
  const int n = DIST_BLOCKS * 3;   // 6144
  float v0 = FLT_MAX, v1 = FLT_MAX, v2 = FLT_MAX;
  int i0 = 0x7fffffff, i1 = 0x7fffffff, i2 = 0x7fffffff;
  for (int j = t; j < n; j += 1024) ins3(topv[j], topi[j], v0, i0, v1, i1, v2, i2);
  for (int off = 32; off; off >>= 1) {
    const float ov0 = __shfl_xor(v0, off, 64);
    const float ov1 = __shfl_xor(v1, off, 64);
    const float ov2 = __shfl_xor(v2, off, 64);
    const int oi0 = __shfl_xor(i0, off, 64);
    const int oi1 = __shfl_xor(i1, off, 64);
    const int oi2 = __shfl_xor(i2, off, 64);
    ins3(ov0, oi0, v0, i0, v1, i1, v2, i2);
    ins3(ov1, oi1, v0, i0, v1, i1, v2, i2);
    ins3(ov2, oi2, v0, i0, v1, i1, v2, i2);
  }
  __shared__ float sv[16][3];
  __shared__ int   si[16][3];
  __shared__ int s_i0, s_cond;
  const int lane = t & 63, wid = t >> 6;
  if (lane == 0) {
    sv[wid][0] = v0; sv[wid][1] = v1; sv[wid][2] = v2;
    si[wid][0] = i0; si[wid][1] = i1; si[wid][2] = i2;
  }
  __syncthreads();
  if (t == 0) {
    for (int w = 1; w < 16; ++w)
      for (int j = 0; j < 3; ++j)
        ins3(sv[w][j], si[w][j], v0, i0, v1, i1, v2, i2);
    const float loss_values = (v0 + 0.5f * v1 + 0.25f * v2) / 1.75f;
    const float wl = ws_winloss[0];
    out_loss[0] = wl + loss_values;
    s_i0 = i0;
    s_cond = (loss_values <= wl) ? 1 : 0;
  }
  __syncthreads();
  if (s_cond) {
    if (t < OUT_DIM) out_mem[(size_t)s_i0 * OUT_DIM + t] = ws_enc[t];
    out_md[(size_t)s_i0 * IN_DIM + t] = x[t];
  }
}

extern "C" void kernel_launch(void* const* d_in, const int* in_sizes, int n_in,
                              void* d_out, int out_size, void* d_ws, size_t ws_size,
                              hipStream_t stream) {
  const float* x        = (const float*)d_in[0];
  const float* mean     = (const float*)d_in[1];
  const float* stdv     = (const float*)d_in[2];
  const float* memory   = (const float*)d_in[3];
  const float* mem_data = (const float*)d_in[4];
  const float* W_enc    = (const float*)d_in[5];
  const float* b_enc    = (const float*)d_in[6];
  const float* W_dec    = (const float*)d_in[7];
  const float* b_dec    = (const float*)d_in[8];
  const float* win_mean = (const float*)d_in[9];
  const float* win_std  = (const float*)d_in[10];

  float* out      = (float*)d_out;
  float* out_loss = out;
  float* out_mem  = out + 1;
  float* out_md   = out + 1 + (size_t)MEM_LEN * OUT_DIM;

  float* ws        = (float*)d_ws;
  float* ws_enc    = ws;                     // 128
  float* ws_wl     = ws + 128;               // 1 (win_loss)
  float* ws_topv   = ws + 256;               // 6144
  int*   ws_topi   = (int*)(ws + 256 + DIST_BLOCKS * 3);   // 6144

  k1_encode<<<1, 1024, 0, stream>>>(x, mean, stdv, W_enc, b_enc, W_dec, b_dec,
                                    win_mean, win_std, ws_enc, ws_wl);
  k2_fused<<<GRID, 256, 0, stream>>>(memory, mem_data, ws_enc, out,
                                     ws_topv, ws_topi);
  k3_topk_update<<<1, 1024, 0, stream>>>(ws_topv, ws_topi, ws_wl, ws_enc, x,
                                         out_loss, out_mem, out_md);
}

// Round 5
// 328.978 us; speedup vs baseline: 1.2889x; 1.2889x over previous
//
#include <hip/hip_runtime.h>
#include <math.h>
#include <float.h>

#define IN_DIM   1024
#define OUT_DIM  128
#define MEM_LEN  131072
#define COPY_GRID 8192
#define DIST_BLOCKS 2048   // 64 rows per block (16 rows/wave * 4 waves)

#define NA_FLOATS  ((long long)MEM_LEN * OUT_DIM)   // 16,777,216
#define NB_FLOATS  ((long long)MEM_LEN * IN_DIM)    // 134,217,728
#define N_TOTAL    (NA_FLOATS + NB_FLOATS)          // 150,994,944
#define NA_CHUNKS  (NA_FLOATS / 4)                  // 4,194,304
#define CMAX       ((N_TOTAL - 4) / 4)              // 37,748,735 last full dst chunk
#define NSPANS     ((CMAX + 255) / 256)             // 147,456 (last span partial)

// insert (v,i) into ascending-(v,i) top-3; lexicographic tie-break matches
// jax.lax.top_k stability (lower index wins on equal distance)
__device__ __forceinline__ void ins3(float v, int i,
    float& v0, int& i0, float& v1, int& i1, float& v2, int& i2) {
  if (v < v0 || (v == v0 && i < i0)) {
    v2 = v1; i2 = i1; v1 = v0; i1 = i0; v0 = v; i0 = i;
  } else if (v < v1 || (v == v1 && i < i1)) {
    v2 = v1; i2 = i1; v1 = v; i1 = i;
  } else if (v < v2 || (v == v2 && i < i2)) {
    v2 = v; i2 = i;
  }
}

// K1: normalize + encoder + decoder-MSE + win_loss. Single block, 1024 threads.
__global__ __launch_bounds__(1024) void k1_encode(
    const float* __restrict__ x, const float* __restrict__ mean,
    const float* __restrict__ stdv, const float* __restrict__ W_enc,
    const float* __restrict__ b_enc, const float* __restrict__ W_dec,
    const float* __restrict__ b_dec, const float* __restrict__ win_mean,
    const float* __restrict__ win_std,
    float* __restrict__ ws_enc, float* __restrict__ ws_winloss) {
  __shared__ float s_new[IN_DIM];
  __shared__ float s_part[8][OUT_DIM];
  __shared__ float s_enc[OUT_DIM];
  __shared__ float s_red[16];
  const int t = threadIdx.x;
  const float sd = stdv[t];
  const float nv = (sd == 0.0f) ? 0.0f : (x[t] - mean[t]) / sd;
  s_new[t] = nv;
  __syncthreads();
  const int o = t & (OUT_DIM - 1);
  const int p = t >> 7;
  float partial = 0.0f;
  #pragma unroll 8
  for (int i = 0; i < 128; ++i) {
    const int k = p * 128 + i;
    partial += s_new[k] * W_enc[k * OUT_DIM + o];
  }
  s_part[p][o] = partial;
  __syncthreads();
  if (t < OUT_DIM) {
    float sum = b_enc[t];
    #pragma unroll
    for (int pp = 0; pp < 8; ++pp) sum += s_part[pp][t];
    const float e = tanhf(sum);
    s_enc[t] = e;
    ws_enc[t] = e;
  }
  __syncthreads();
  float r = b_dec[t];
  #pragma unroll 8
  for (int k = 0; k < OUT_DIM; ++k) r += s_enc[k] * W_dec[k * IN_DIM + t];
  const float diff = r - nv;
  float sq = diff * diff;
  for (int off = 32; off; off >>= 1) sq += __shfl_xor(sq, off, 64);
  const int lane = t & 63, wid = t >> 6;
  if (lane == 0) s_red[wid] = sq;
  __syncthreads();
  if (t == 0) {
    float tot = 0.0f;
    #pragma unroll
    for (int w = 0; w < 16; ++w) tot += s_red[w];
    const float mse = tot / (float)IN_DIM;
    const float z = (mse - win_mean[0]) / win_std[0];
    const float prob = 0.5f * erfcf(-z * 0.70710678118654752440f); // ndtr
    ws_winloss[0] = (1.0f - prob) * mse;  // SKIP_THRESHOLD == 1
  }
}

// K2: L1 distances. float4 loads (2 rows per wave-instruction, 1KB contig),
// 5-level shfl reduce within each 32-lane half, 16 rows per wave.
__global__ __launch_bounds__(256) void k2_dist(
    const float* __restrict__ memory, const float* __restrict__ ws_enc,
    float* __restrict__ topv, int* __restrict__ topi) {
  const int t = threadIdx.x;
  const int lane = t & 63;
  const int wid = t >> 6;
  const int half = lane >> 5;            // row parity within pair
  const int col  = lane & 31;            // float4 column within row
  const float4 e = reinterpret_cast<const float4*>(ws_enc)[col];
  const float4* m4 = reinterpret_cast<const float4*>(memory);
  float v0 = FLT_MAX, v1 = FLT_MAX, v2 = FLT_MAX;
  int i0 = 0x7fffffff, i1 = 0x7fffffff, i2 = 0x7fffffff;
  const int r0 = (blockIdx.x * 4 + wid) * 16;
  for (int rr = 0; rr < 16; rr += 2) {
    const float4 m = m4[(size_t)(r0 + rr) * 32 + lane];
    float d = fabsf(m.x - e.x) + fabsf(m.y - e.y)
            + fabsf(m.z - e.z) + fabsf(m.w - e.w);
    d += __shfl_xor(d, 1, 64);
    d += __shfl_xor(d, 2, 64);
    d += __shfl_xor(d, 4, 64);
    d += __shfl_xor(d, 8, 64);
    d += __shfl_xor(d, 16, 64);          // replicated within each 32-half
    ins3(d, r0 + rr + half, v0, i0, v1, i1, v2, i2);
  }
  // merge the two halves' top3
  {
    const float w0 = __shfl_xor(v0, 32, 64);
    const float w1 = __shfl_xor(v1, 32, 64);
    const float w2 = __shfl_xor(v2, 32, 64);
    const int j0 = __shfl_xor(i0, 32, 64);
    const int j1 = __shfl_xor(i1, 32, 64);
    const int j2 = __shfl_xor(i2, 32, 64);
    ins3(w0, j0, v0, i0, v1, i1, v2, i2);
    ins3(w1, j1, v0, i0, v1, i1, v2, i2);
    ins3(w2, j2, v0, i0, v1, i1, v2, i2);
  }
  __shared__ float sv[4][3];
  __shared__ int   si[4][3];
  if (lane == 0) {
    sv[wid][0] = v0; sv[wid][1] = v1; sv[wid][2] = v2;
    si[wid][0] = i0; si[wid][1] = i1; si[wid][2] = i2;
  }
  __syncthreads();
  if (t == 0) {
    for (int w = 1; w < 4; ++w)
      for (int j = 0; j < 3; ++j)
        ins3(sv[w][j], si[w][j], v0, i0, v1, i1, v2, i2);
    topv[blockIdx.x * 3 + 0] = v0; topi[blockIdx.x * 3 + 0] = i0;
    topv[blockIdx.x * 3 + 1] = v1; topi[blockIdx.x * 3 + 1] = i1;
    topv[blockIdx.x * 3 + 2] = v2; topi[blockIdx.x * 3 + 2] = i2;
  }
}

// Realigned copy out[1..N_TOTAL] <- {memory, mem_data}.
// Span = 256 chunks (4KB) per wave-iteration. Lane L owns chunks
// base+L+{0,64,128,192}: every load/store instruction is 1KB CONTIGUOUS
// across the wave; realign dword comes from shfl_up (lane>0) / broadcast
// shfl from lane 63 of the previous quarter (lane 0), one scalar dword for
// the span edge.
__global__ __launch_bounds__(256) void copy_all(
    const float* __restrict__ memory, const float* __restrict__ mem_data,
    float* __restrict__ out) {
  const int t = threadIdx.x;
  const int lane = t & 63;
  const int wid  = t >> 6;
  const float4* mem4 = reinterpret_cast<const float4*>(memory);
  const float4* md4  = reinterpret_cast<const float4*>(mem_data);
  float4* out4 = reinterpret_cast<float4*>(out);
  const long long wstride = (long long)gridDim.x * 4;
  for (long long s = (long long)blockIdx.x * 4 + wid; s < NSPANS; s += wstride) {
    const long long base = 1 + s * 256;
    const long long sdw = 4 * base - 1;  // flat src dword for lane0 chunk0 realign
    const float edge = (sdw < NA_FLOATS) ? memory[sdw] : mem_data[sdw - NA_FLOATS];
    if (s < NSPANS - 1 && (base + 256 <= NA_CHUNKS || base >= NA_CHUNKS)) {
      // fast path: full span, single source region
      const float4* src = (base >= NA_CHUNKS) ? (md4 - NA_CHUNKS) : mem4;
      const long long cL = base + lane;
      const float4 a0 = src[cL];
      const float4 a1 = src[cL + 64];
      const float4 a2 = src[cL + 128];
      const float4 a3 = src[cL + 192];
      float p0 = __shfl_up(a0.w, 1, 64);
      float p1 = __shfl_up(a1.w, 1, 64);
      float p2 = __shfl_up(a2.w, 1, 64);
      float p3 = __shfl_up(a3.w, 1, 64);
      const float t1 = __shfl(a0.w, 63, 64);
      const float t2 = __shfl(a1.w, 63, 64);
      const float t3 = __shfl(a2.w, 63, 64);
      if (lane == 0) { p0 = edge; p1 = t1; p2 = t2; p3 = t3; }
      out4[cL]       = make_float4(p0, a0.x, a0.y, a0.z);
      out4[cL + 64]  = make_float4(p1, a1.x, a1.y, a1.z);
      out4[cL + 128] = make_float4(p2, a2.x, a2.y, a2.z);
      out4[cL + 192] = make_float4(p3, a3.x, a3.y, a3.z);
    } else {
      // slow path (2 spans total): per-chunk region/validity guards
      float4 a[4];
      #pragma unroll
      for (int k = 0; k < 4; ++k) {
        const long long c = base + k * 64 + lane;
        a[k] = (c <= CMAX)
                 ? ((c < NA_CHUNKS) ? mem4[c] : md4[c - NA_CHUNKS])
                 : make_float4(0.f, 0.f, 0.f, 0.f);
      }
      float p0 = __shfl_up(a[0].w, 1, 64);
      float p1 = __shfl_up(a[1].w, 1, 64);
      float p2 = __shfl_up(a[2].w, 1, 64);
      float p3 = __shfl_up(a[3].w, 1, 64);
      const float t1 = __shfl(a[0].w, 63, 64);
      const float t2 = __shfl(a[1].w, 63, 64);
      const float t3 = __shfl(a[2].w, 63, 64);
      if (lane == 0) { p0 = edge; p1 = t1; p2 = t2; p3 = t3; }
      const float pw[4] = {p0, p1, p2, p3};
      #pragma unroll
      for (int k = 0; k < 4; ++k) {
        const long long c = base + k * 64 + lane;
        if (c <= CMAX)
          out4[c] = make_float4(pw[k], a[k].x, a[k].y, a[k].z);
      }
    }
  }
  if (blockIdx.x == 0 && t == 0) {
    out[1] = memory[0]; out[2] = memory[1]; out[3] = memory[2];
    out[N_TOTAL] = mem_data[NB_FLOATS - 1];
  }
}

// K3+K4: merge candidates, final loss, conditional FIFO row update.
__global__ __launch_bounds__(1024) void k3_topk_update(
    const float* __restrict__ topv, const int* __restrict__ topi,
    const float* __restrict__ ws_winloss, const float* __restrict__ ws_enc,
    const float* __restrict__ x, float* __restrict__ out_loss,
    float* __restrict__ out_mem, float* __restrict__ out_md) {
  const int t = threadIdx.x;
  const int n = DIST_BLOCKS * 3;   // 6144
  float v0 = FLT_MAX, v1 = FLT_MAX, v2 = FLT_MAX;
  int i0 = 0x7fffffff, i1 = 0x7fffffff, i2 = 0x7fffffff;
  for (int j = t; j < n; j += 1024) ins3(topv[j], topi[j], v0, i0, v1, i1, v2, i2);
  for (int off = 32; off; off >>= 1) {
    const float ov0 = __shfl_xor(v0, off, 64);
    const float ov1 = __shfl_xor(v1, off, 64);
    const float ov2 = __shfl_xor(v2, off, 64);
    const int oi0 = __shfl_xor(i0, off, 64);
    const int oi1 = __shfl_xor(i1, off, 64);
    const int oi2 = __shfl_xor(i2, off, 64);
    ins3(ov0, oi0, v0, i0, v1, i1, v2, i2);
    ins3(ov1, oi1, v0, i0, v1, i1, v2, i2);
    ins3(ov2, oi2, v0, i0, v1, i1, v2, i2);
  }
  __shared__ float sv[16][3];
  __shared__ int   si[16][3];
  __shared__ int s_i0, s_cond;
  const int lane = t & 63, wid = t >> 6;
  if (lane == 0) {
    sv[wid][0] = v0; sv[wid][1] = v1; sv[wid][2] = v2;
    si[wid][0] = i0; si[wid][1] = i1; si[wid][2] = i2;
  }
  __syncthreads();
  if (t == 0) {
    for (int w = 1; w < 16; ++w)
      for (int j = 0; j < 3; ++j)
        ins3(sv[w][j], si[w][j], v0, i0, v1, i1, v2, i2);
    const float loss_values = (v0 + 0.5f * v1 + 0.25f * v2) / 1.75f;
    const float wl = ws_winloss[0];
    out_loss[0] = wl + loss_values;
    s_i0 = i0;
    s_cond = (loss_values <= wl) ? 1 : 0;
  }
  __syncthreads();
  if (s_cond) {
    if (t < OUT_DIM) out_mem[(size_t)s_i0 * OUT_DIM + t] = ws_enc[t];
    out_md[(size_t)s_i0 * IN_DIM + t] = x[t];
  }
}

extern "C" void kernel_launch(void* const* d_in, const int* in_sizes, int n_in,
                              void* d_out, int out_size, void* d_ws, size_t ws_size,
                              hipStream_t stream) {
  const float* x        = (const float*)d_in[0];
  const float* mean     = (const float*)d_in[1];
  const float* stdv     = (const float*)d_in[2];
  const float* memory   = (const float*)d_in[3];
  const float* mem_data = (const float*)d_in[4];
  const float* W_enc    = (const float*)d_in[5];
  const float* b_enc    = (const float*)d_in[6];
  const float* W_dec    = (const float*)d_in[7];
  const float* b_dec    = (const float*)d_in[8];
  const float* win_mean = (const float*)d_in[9];
  const float* win_std  = (const float*)d_in[10];

  float* out      = (float*)d_out;
  float* out_loss = out;
  float* out_mem  = out + 1;
  float* out_md   = out + 1 + (size_t)MEM_LEN * OUT_DIM;

  float* ws        = (float*)d_ws;
  float* ws_enc    = ws;                     // 128
  float* ws_wl     = ws + 128;               // 1 (win_loss)
  float* ws_topv   = ws + 256;               // 6144
  int*   ws_topi   = (int*)(ws + 256 + DIST_BLOCKS * 3);   // 6144

  k1_encode<<<1, 1024, 0, stream>>>(x, mean, stdv, W_enc, b_enc, W_dec, b_dec,
                                    win_mean, win_std, ws_enc, ws_wl);
  k2_dist<<<DIST_BLOCKS, 256, 0, stream>>>(memory, ws_enc, ws_topv, ws_topi);
  copy_all<<<COPY_GRID, 256, 0, stream>>>(memory, mem_data, out);
  k3_topk_update<<<1, 1024, 0, stream>>>(ws_topv, ws_topi, ws_wl, ws_enc, x,
                                         out_loss, out_mem, out_md);
}